// Round 13
// baseline (194.422 us; speedup 1.0000x reference)
//
#include <hip/hip_runtime.h>

// VQ-VAE vector quantizer. Round 13: kill the tail (6 kernels -> 4).
// z: [16,64,32,32] f32, emb: [8192,64] f32. N=16384 pts, C=64, V=8192.
// out = [ z_q_st (1048576) | idx as f32 (16384) | vq_loss (1) ]
//
// R12 post-mortem: k1=43.7 (VALU 44%, unexplained 2x — parked); non-k1 = 114us
// vs ~35us bottom-up estimate -> launch gaps + small-kernel overhead.
// R13: k_pre 4x parallelism; k1 float2-packed ps/p2 stores; k2+rescue FUSED
// (spin barrier, 256 blocks = 1/CU co-resident); loss finalize fused into k3
// (done-counter, last block reduces). 2 fewer launches/gaps.

typedef _Float16 half8 __attribute__((ext_vector_type(8)));
typedef float f32x4 __attribute__((ext_vector_type(4)));

#define N_PTS 16384
#define SPLITS 16
#define THR16 0.08f   // fp16-score error bound (10 sigma), validated R3-R12

// ---------------- k_pre: 4 threads per code row ----------------
// thread (v, part): channels part*16..+15. Norm via shfl within 4-lane group.
__global__ __launch_bounds__(256) void k_pre(const float* __restrict__ emb,
                                             float* __restrict__ hneg,
                                             unsigned short* __restrict__ e16,
                                             float* __restrict__ embT,
                                             int* __restrict__ cnt) {
  int t = blockIdx.x * 256 + threadIdx.x;   // grid 128 -> 32768
  int v = t >> 2, part = t & 3;
  const float4* e4 = (const float4*)(emb + v * 64 + part * 16);
  float row[16];
  float s = 0.f;
#pragma unroll
  for (int i = 0; i < 4; ++i) {
    float4 a = e4[i];
    row[i * 4 + 0] = a.x; row[i * 4 + 1] = a.y;
    row[i * 4 + 2] = a.z; row[i * 4 + 3] = a.w;
    s += a.x * a.x + a.y * a.y + a.z * a.z + a.w * a.w;
  }
  // full ||e||^2 across the 4 parts (lanes 4v..4v+3 contiguous in a wave)
  s += __shfl_xor(s, 1);
  s += __shfl_xor(s, 2);
  // e16 swizzled: this thread owns c8 groups part*2, part*2+1
  unsigned short* base = e16 + (v >> 4) * 1024 + (v & 15) * 8;
#pragma unroll
  for (int g = 0; g < 2; ++g) {
    int c8 = part * 2 + g;
    half8 o;
#pragma unroll
    for (int j = 0; j < 8; ++j) o[j] = (_Float16)row[g * 8 + j];
    *(half8*)(base + (c8 >> 2) * 512 + (c8 & 3) * 128) = o;
  }
  // fp32 transpose: embT[c][v]
#pragma unroll
  for (int i = 0; i < 16; ++i) embT[(part * 16 + i) * 8192 + v] = row[i];
  if (part == 0) hneg[v] = -0.5f * s;
  if (t == 0) { cnt[0] = 0; cnt[1] = 0; cnt[2] = 0; }  // cnt, done2, done3
}

// ---------------- k1: MFMA scores, packed-index top-2, pt=4 ----------------
// grid (64, 16). block 256 = 4 waves; wave owns 64 points (4 tiles of 16),
// sweeps 512 codes (32 tiles). 1024 blocks = 4 blocks/CU.
__global__ __launch_bounds__(256, 4) void k1_score(
    const float* __restrict__ z, const unsigned short* __restrict__ e16,
    const float* __restrict__ hneg,
    float2* __restrict__ psp) {
  __shared__ float hs[512];
  const int tid = threadIdx.x;
  const int lane = tid & 63;
  const int wid = tid >> 6;
  const int cl = lane & 15;     // A row (point) / B col (code) within tile
  const int gq = lane >> 4;     // quad: selects k-slice / C rows
  const int n0 = blockIdx.x * 256 + wid * 64;
  const int split = blockIdx.y;
  const int vbase = split * 512;

  *(float2*)&hs[tid * 2] = *(const float2*)(hneg + vbase + tid * 2);
  __syncthreads();

  const int b = n0 >> 10;
  const int hw0 = n0 & 1023;

  half8 A[4][2];
  {
    const float* zb = z + b * 65536 + hw0 + cl;
#pragma unroll
    for (int pt = 0; pt < 4; ++pt)
#pragma unroll
      for (int H = 0; H < 2; ++H) {
        half8 a;
#pragma unroll
        for (int j = 0; j < 8; ++j)
          a[j] = (_Float16)zb[pt * 16 + (H * 32 + gq * 8 + j) * 1024];
        A[pt][H] = a;
      }
  }

  float s1[4][4], s2[4][4];
#pragma unroll
  for (int pt = 0; pt < 4; ++pt)
#pragma unroll
    for (int r = 0; r < 4; ++r) { s1[pt][r] = -3.0e38f; s2[pt][r] = -3.0e38f; }

  const unsigned short* bbase = e16 + vbase * 64 + lane * 8;
  int idxb = 8191 - (vbase + cl);   // packed-index field, decrements 16/tile

#pragma unroll 2
  for (int T = 0; T < 32; ++T) {
    const unsigned short* bp = bbase + T * 1024;
    half8 B0 = *(const half8*)bp;
    half8 B1 = *(const half8*)(bp + 512);
    const float nh = hs[T * 16 + cl];
    f32x4 C0;
    C0[0] = nh; C0[1] = nh; C0[2] = nh; C0[3] = nh;   // -h as MFMA C operand

#pragma unroll
    for (int pt = 0; pt < 4; ++pt) {
      f32x4 acc = __builtin_amdgcn_mfma_f32_16x16x32_f16(A[pt][0], B0, C0, 0, 0, 0);
      acc = __builtin_amdgcn_mfma_f32_16x16x32_f16(A[pt][1], B1, acc, 0, 0, 0);
#pragma unroll
      for (int r = 0; r < 4; ++r) {
        unsigned u = (__float_as_uint(acc[r]) & 0xFFFFE000u) | (unsigned)idxb;
        float p = __uint_as_float(u);
        s2[pt][r] = __builtin_amdgcn_fmed3f(p, s1[pt][r], s2[pt][r]);
        s1[pt][r] = fmaxf(s1[pt][r], p);
      }
    }
    idxb -= 16;
  }

  // butterfly merge across the 16 cols (index rides inside s1/s2)
#pragma unroll
  for (int off = 8; off >= 1; off >>= 1) {
#pragma unroll
    for (int pt = 0; pt < 4; ++pt)
#pragma unroll
      for (int r = 0; r < 4; ++r) {
        float os = __shfl_xor(s1[pt][r], off);
        float o2 = __shfl_xor(s2[pt][r], off);
        s2[pt][r] = fmaxf(fmaxf(s2[pt][r], o2), fminf(s1[pt][r], os));
        s1[pt][r] = fmaxf(s1[pt][r], os);
      }
  }

  if (cl == 0) {
#pragma unroll
    for (int pt = 0; pt < 4; ++pt)
#pragma unroll
      for (int r = 0; r < 4; ++r) {
        int n = n0 + pt * 16 + gq * 4 + r;     // C row = gq*4 + reg
        float2 o; o.x = s1[pt][r]; o.y = s2[pt][r];
        psp[split * N_PTS + n] = o;
      }
  }
}

// ---------------- k_mr: fused merge + rescue (spin barrier) ----------------
// grid 256 x 1024 = 1 block/CU (co-resident by construction).
// Phase M: 64 pts/block merged from 16 splits, idx emitted, margin list built.
// Spin barrier on done2. Phase R: exact-fp32 rescue, 8 pts per block-pass.
__global__ __launch_bounds__(1024, 1) void k_mr(
    const float* __restrict__ z, const float* __restrict__ embT,
    const float* __restrict__ hneg, const float2* __restrict__ psp,
    int* __restrict__ idxf, float* __restrict__ out_idx,
    int* __restrict__ list, int* __restrict__ cnt) {
  __shared__ float zsT[64][8];
  __shared__ int pn[8];
  __shared__ float rs[16][8], ri[16][8];
  __shared__ int cntS;
  const int tid = threadIdx.x;
  const int lane = tid & 63, wv = tid >> 6;
  int* done2 = cnt + 1;

  // ---- phase M ----
  if (tid < 64) {
    int n = blockIdx.x * 64 + tid;
    float S1 = -3.0e38f, S2 = -3.0e38f;
#pragma unroll
    for (int s = 0; s < SPLITS; ++s) {
      float2 a = psp[s * N_PTS + n];
      if (a.x > S1) { S2 = fmaxf(fmaxf(S2, a.y), S1); S1 = a.x; }
      else          { S2 = fmaxf(S2, a.x); }
    }
    int I1 = 8191 - (int)(__float_as_uint(S1) & 0x1FFFu);
    idxf[n] = I1;
    out_idx[n] = (float)I1;
    // packing truncation error <= |S|*2^-10 per score; compensate exactly
    float q = fmaxf(fabsf(S1), fabsf(S2)) * 0.0009765625f;
    if (S1 - S2 < THR16 + q) {
      int p = atomicAdd(cnt, 1);
      list[p] = n;
    }
  }
  __syncthreads();
  // ---- device barrier (all 256 blocks co-resident) ----
  if (tid == 0) {
    __threadfence();
    atomicAdd(done2, 1);
    while (__hip_atomic_load(done2, __ATOMIC_ACQUIRE, __HIP_MEMORY_SCOPE_AGENT) < 256)
      __builtin_amdgcn_s_sleep(16);
    cntS = __hip_atomic_load(cnt, __ATOMIC_ACQUIRE, __HIP_MEMORY_SCOPE_AGENT);
  }
  __syncthreads();
  const int count = cntS;

  // ---- phase R: rescue (8 codes/thread, 8 pts/block-pass) ----
  for (int base = blockIdx.x * 8; base < count; base += 256 * 8) {
    const int P = min(8, count - base);
    __syncthreads();
    if (tid < 8) pn[tid] = list[base + min(tid, P - 1)];  // pad with last valid
    __syncthreads();
    if (tid < 512) {
      int p = tid >> 6, c = tid & 63;
      int n = pn[p];
      zsT[c][p] = z[(n >> 10) * 65536 + c * 1024 + (n & 1023)];
    }
    __syncthreads();

    float d[64];
#pragma unroll
    for (int i = 0; i < 64; ++i) d[i] = 0.f;

    const float4* eT = (const float4*)embT;   // rows of 2048 float4
    float4 cur0 = eT[tid];                    // c=0, codes 4t..4t+3
    float4 cur1 = eT[1024 + tid];             // c=0, codes 4096+4t..+3

    for (int c = 0; c < 64; ++c) {
      float4 nxt0, nxt1;
      if (c < 63) {
        const float4* rowp = eT + (c + 1) * 2048 + tid;
        nxt0 = rowp[0];
        nxt1 = rowp[1024];
      }
      float4 zpA = *(const float4*)&zsT[c][0];   // broadcast, conflict-free
      float4 zpB = *(const float4*)&zsT[c][4];
#pragma unroll
      for (int k = 0; k < 8; ++k) {
        float e = (k == 0) ? cur0.x : (k == 1) ? cur0.y : (k == 2) ? cur0.z :
                  (k == 3) ? cur0.w : (k == 4) ? cur1.x : (k == 5) ? cur1.y :
                  (k == 6) ? cur1.z : cur1.w;
        float* dp = d + k * 8;
        dp[0] = fmaf(e, zpA.x, dp[0]); dp[1] = fmaf(e, zpA.y, dp[1]);
        dp[2] = fmaf(e, zpA.z, dp[2]); dp[3] = fmaf(e, zpA.w, dp[3]);
        dp[4] = fmaf(e, zpB.x, dp[4]); dp[5] = fmaf(e, zpB.y, dp[5]);
        dp[6] = fmaf(e, zpB.z, dp[6]); dp[7] = fmaf(e, zpB.w, dp[7]);
      }
      if (c < 63) { cur0 = nxt0; cur1 = nxt1; }
    }

    float4 hv0 = *(const float4*)(hneg + tid * 4);
    float4 hv1 = *(const float4*)(hneg + 4096 + tid * 4);
    float bs[8], bi[8];
#pragma unroll
    for (int p = 0; p < 8; ++p) { bs[p] = -3.0e38f; bi[p] = 0.f; }
#pragma unroll
    for (int k = 0; k < 8; ++k) {
      float hk = (k == 0) ? hv0.x : (k == 1) ? hv0.y : (k == 2) ? hv0.z :
                 (k == 3) ? hv0.w : (k == 4) ? hv1.x : (k == 5) ? hv1.y :
                 (k == 6) ? hv1.z : hv1.w;
      float cf = (float)((k < 4 ? 0 : 4096) + tid * 4 + (k & 3));
#pragma unroll
      for (int p = 0; p < 8; ++p) {
        float sc = d[k * 8 + p] + hk;
        if (sc > bs[p]) { bs[p] = sc; bi[p] = cf; }
      }
    }

#pragma unroll
    for (int off = 32; off >= 1; off >>= 1) {
#pragma unroll
      for (int p = 0; p < 8; ++p) {
        float os = __shfl_xor(bs[p], off);
        float oi = __shfl_xor(bi[p], off);
        if (os > bs[p] || (os == bs[p] && oi < bi[p])) { bs[p] = os; bi[p] = oi; }
      }
    }
    if (lane == 0)
#pragma unroll
      for (int p = 0; p < 8; ++p) { rs[wv][p] = bs[p]; ri[wv][p] = bi[p]; }
    __syncthreads();
    if (tid < 8) {
      int p = tid;
      float s = rs[0][p], i = ri[0][p];
#pragma unroll
      for (int w = 1; w < 16; ++w) {
        if (rs[w][p] > s || (rs[w][p] == s && ri[w][p] < i)) { s = rs[w][p]; i = ri[w][p]; }
      }
      if (p < P) {
        int n = pn[p];
        idxf[n] = (int)i;
        out_idx[n] = i;
      }
    }
  }
}

// ---------------- k3: gather, ST out, loss partial + fused finalize ----------
__global__ __launch_bounds__(256) void k3_quant(
    const float* __restrict__ z, const float* __restrict__ emb,
    const int* __restrict__ idxf,
    float* __restrict__ out, float* __restrict__ psum, int* __restrict__ done3,
    float* __restrict__ out_loss) {
  int t = blockIdx.x * 256 + threadIdx.x;   // grid 1024 -> 262144 float4 slots
  int g = t * 4;
  int b = g >> 16;
  int c = (g >> 10) & 63;
  int hw = g & 1023;
  int n = (b << 10) | hw;                   // n..n+3, 4-aligned
  float4 zv = *(const float4*)(z + g);
  int4 iv = *(const int4*)(idxf + n);
  float q0 = emb[iv.x * 64 + c];
  float q1 = emb[iv.y * 64 + c];
  float q2 = emb[iv.z * 64 + c];
  float q3 = emb[iv.w * 64 + c];
  float d0 = q0 - zv.x, d1 = q1 - zv.y, d2 = q2 - zv.z, d3 = q3 - zv.w;
  float4 o;
  o.x = zv.x + d0; o.y = zv.y + d1; o.z = zv.z + d2; o.w = zv.w + d3;
  *(float4*)(out + g) = o;
  float val = d0 * d0 + d1 * d1 + d2 * d2 + d3 * d3;
#pragma unroll
  for (int off = 32; off >= 1; off >>= 1) val += __shfl_down(val, off);
  __shared__ float wsum[4];
  __shared__ int lastS;
  int lane = threadIdx.x & 63, wv = threadIdx.x >> 6;
  if (lane == 0) wsum[wv] = val;
  __syncthreads();
  if (threadIdx.x == 0) {
    psum[blockIdx.x] = wsum[0] + wsum[1] + wsum[2] + wsum[3];
    __threadfence();
    lastS = (atomicAdd(done3, 1) == 1023) ? 1 : 0;
  }
  __syncthreads();
  if (lastS) {
    // last block: reduce all 1024 partials
    float v = 0.f;
#pragma unroll
    for (int i = 0; i < 4; ++i)
      v += __hip_atomic_load(&psum[threadIdx.x + i * 256], __ATOMIC_RELAXED,
                             __HIP_MEMORY_SCOPE_AGENT);
#pragma unroll
    for (int off = 32; off >= 1; off >>= 1) v += __shfl_down(v, off);
    __syncthreads();
    if (lane == 0) wsum[wv] = v;
    __syncthreads();
    if (threadIdx.x == 0)
      out_loss[0] = 1.25f * (wsum[0] + wsum[1] + wsum[2] + wsum[3]) * (1.0f / 1048576.0f);
  }
}

extern "C" void kernel_launch(void* const* d_in, const int* in_sizes, int n_in,
                              void* d_out, int out_size, void* d_ws, size_t ws_size,
                              hipStream_t stream) {
  const float* z   = (const float*)d_in[0];
  const float* emb = (const float*)d_in[1];
  float* out = (float*)d_out;
  float* ws  = (float*)d_ws;

  float* hneg = ws;                                   // 8192
  unsigned short* e16 = (unsigned short*)(ws + 8192); // 524288 halfs = 262144 f
  float* embT = ws + 8192 + 262144;                   // 524288 (fp32 transpose)
  float2* psp = (float2*)(embT + 524288);             // 16*16384 float2
  int* idxf  = (int*)(psp + SPLITS * N_PTS);          // 16384
  int* list  = idxf + N_PTS;                          // 16384
  int* cnt   = list + N_PTS;                          // cnt, done2, done3
  float* psum = (float*)(cnt + 3);                    // 1024

  float* out_idx  = out + 1048576;
  float* out_loss = out + 1048576 + 16384;

  k_pre<<<128, 256, 0, stream>>>(emb, hneg, e16, embT, cnt);
  k1_score<<<dim3(64, SPLITS), 256, 0, stream>>>(z, e16, hneg, psp);
  k_mr<<<256, 1024, 0, stream>>>(z, embT, hneg, psp, idxf, out_idx, list, cnt);
  k3_quant<<<1024, 256, 0, stream>>>(z, emb, idxf, out, psum, cnt + 2, out_loss);
}

// Round 14
// 177.226 us; speedup vs baseline: 1.0970x; 1.0970x over previous
//
#include <hip/hip_runtime.h>

// VQ-VAE vector quantizer. Round 14.
// z: [16,64,32,32] f32, emb: [8192,64] f32. N=16384 pts, C=64, V=8192.
// out = [ z_q_st (1048576) | idx as f32 (16384) | vq_loss (1) ]
//
// R13 post-mortem: fused k_mr regressed (66us, VALU 10%): 8-pts/block off a
// ~600 list -> 75/256 blocks busy, each a full 2MB latency-chained sweep.
// R14: un-fuse; rescue decomposed 2-D: task = (8-pt group) x (1024-code
// chunk) -> ~608 tasks on 1024 blocks, 256KB/task. Cross-chunk merge via
// EXACT atomicMax(u64: sortable-score<<32 | 8191-code); last block converts.

typedef _Float16 half8 __attribute__((ext_vector_type(8)));
typedef float f32x4 __attribute__((ext_vector_type(4)));

#define N_PTS 16384
#define SPLITS 16
#define THR16 0.08f   // fp16-score error bound (10 sigma), validated R3-R13

// ---------------- k_pre: 4 threads per code row ----------------
__global__ __launch_bounds__(256) void k_pre(const float* __restrict__ emb,
                                             float* __restrict__ hneg,
                                             unsigned short* __restrict__ e16,
                                             float* __restrict__ embT,
                                             int* __restrict__ cnt) {
  int t = blockIdx.x * 256 + threadIdx.x;   // grid 128 -> 32768
  int v = t >> 2, part = t & 3;
  const float4* e4 = (const float4*)(emb + v * 64 + part * 16);
  float row[16];
  float s = 0.f;
#pragma unroll
  for (int i = 0; i < 4; ++i) {
    float4 a = e4[i];
    row[i * 4 + 0] = a.x; row[i * 4 + 1] = a.y;
    row[i * 4 + 2] = a.z; row[i * 4 + 3] = a.w;
    s += a.x * a.x + a.y * a.y + a.z * a.z + a.w * a.w;
  }
  s += __shfl_xor(s, 1);
  s += __shfl_xor(s, 2);
  unsigned short* base = e16 + (v >> 4) * 1024 + (v & 15) * 8;
#pragma unroll
  for (int g = 0; g < 2; ++g) {
    int c8 = part * 2 + g;
    half8 o;
#pragma unroll
    for (int j = 0; j < 8; ++j) o[j] = (_Float16)row[g * 8 + j];
    *(half8*)(base + (c8 >> 2) * 512 + (c8 & 3) * 128) = o;
  }
#pragma unroll
  for (int i = 0; i < 16; ++i) embT[(part * 16 + i) * 8192 + v] = row[i];
  if (part == 0) hneg[v] = -0.5f * s;
  if (t == 0) { cnt[0] = 0; cnt[1] = 0; cnt[2] = 0; }  // cnt, rdone, done3
}

// ---------------- k1: MFMA scores, packed-index top-2, pt=4 ----------------
// grid (64, 16). block 256 = 4 waves; wave owns 64 points (4 tiles of 16),
// sweeps 512 codes (32 tiles). 1024 blocks = 4 blocks/CU.
__global__ __launch_bounds__(256, 4) void k1_score(
    const float* __restrict__ z, const unsigned short* __restrict__ e16,
    const float* __restrict__ hneg,
    float2* __restrict__ psp) {
  __shared__ float hs[512];
  const int tid = threadIdx.x;
  const int lane = tid & 63;
  const int wid = tid >> 6;
  const int cl = lane & 15;
  const int gq = lane >> 4;
  const int n0 = blockIdx.x * 256 + wid * 64;
  const int split = blockIdx.y;
  const int vbase = split * 512;

  *(float2*)&hs[tid * 2] = *(const float2*)(hneg + vbase + tid * 2);
  __syncthreads();

  const int b = n0 >> 10;
  const int hw0 = n0 & 1023;

  half8 A[4][2];
  {
    const float* zb = z + b * 65536 + hw0 + cl;
#pragma unroll
    for (int pt = 0; pt < 4; ++pt)
#pragma unroll
      for (int H = 0; H < 2; ++H) {
        half8 a;
#pragma unroll
        for (int j = 0; j < 8; ++j)
          a[j] = (_Float16)zb[pt * 16 + (H * 32 + gq * 8 + j) * 1024];
        A[pt][H] = a;
      }
  }

  float s1[4][4], s2[4][4];
#pragma unroll
  for (int pt = 0; pt < 4; ++pt)
#pragma unroll
    for (int r = 0; r < 4; ++r) { s1[pt][r] = -3.0e38f; s2[pt][r] = -3.0e38f; }

  const unsigned short* bbase = e16 + vbase * 64 + lane * 8;
  int idxb = 8191 - (vbase + cl);

#pragma unroll 2
  for (int T = 0; T < 32; ++T) {
    const unsigned short* bp = bbase + T * 1024;
    half8 B0 = *(const half8*)bp;
    half8 B1 = *(const half8*)(bp + 512);
    const float nh = hs[T * 16 + cl];
    f32x4 C0;
    C0[0] = nh; C0[1] = nh; C0[2] = nh; C0[3] = nh;

#pragma unroll
    for (int pt = 0; pt < 4; ++pt) {
      f32x4 acc = __builtin_amdgcn_mfma_f32_16x16x32_f16(A[pt][0], B0, C0, 0, 0, 0);
      acc = __builtin_amdgcn_mfma_f32_16x16x32_f16(A[pt][1], B1, acc, 0, 0, 0);
#pragma unroll
      for (int r = 0; r < 4; ++r) {
        unsigned u = (__float_as_uint(acc[r]) & 0xFFFFE000u) | (unsigned)idxb;
        float p = __uint_as_float(u);
        s2[pt][r] = __builtin_amdgcn_fmed3f(p, s1[pt][r], s2[pt][r]);
        s1[pt][r] = fmaxf(s1[pt][r], p);
      }
    }
    idxb -= 16;
  }

#pragma unroll
  for (int off = 8; off >= 1; off >>= 1) {
#pragma unroll
    for (int pt = 0; pt < 4; ++pt)
#pragma unroll
      for (int r = 0; r < 4; ++r) {
        float os = __shfl_xor(s1[pt][r], off);
        float o2 = __shfl_xor(s2[pt][r], off);
        s2[pt][r] = fmaxf(fmaxf(s2[pt][r], o2), fminf(s1[pt][r], os));
        s1[pt][r] = fmaxf(s1[pt][r], os);
      }
  }

  if (cl == 0) {
#pragma unroll
    for (int pt = 0; pt < 4; ++pt)
#pragma unroll
      for (int r = 0; r < 4; ++r) {
        int n = n0 + pt * 16 + gq * 4 + r;
        float2 o; o.x = s1[pt][r]; o.y = s2[pt][r];
        psp[split * N_PTS + n] = o;
      }
  }
}

// ---------------- k2: merge splits (packed), exact-q margin, emit idx --------
__global__ __launch_bounds__(256) void k2_merge(
    const float2* __restrict__ psp,
    int* __restrict__ idxf, float* __restrict__ out_idx,
    int* __restrict__ list, int* __restrict__ cnt,
    unsigned long long* __restrict__ rpack) {
  int n = blockIdx.x * 256 + threadIdx.x;   // grid 64 -> 16384
  float S1 = -3.0e38f, S2 = -3.0e38f;
#pragma unroll
  for (int s = 0; s < SPLITS; ++s) {
    float2 a = psp[s * N_PTS + n];
    if (a.x > S1) { S2 = fmaxf(fmaxf(S2, a.y), S1); S1 = a.x; }
    else          { S2 = fmaxf(S2, a.x); }
  }
  int I1 = 8191 - (int)(__float_as_uint(S1) & 0x1FFFu);
  idxf[n] = I1;
  out_idx[n] = (float)I1;
  // packing truncation error <= |S|*2^-10 per score; compensate exactly
  float q = fmaxf(fabsf(S1), fabsf(S2)) * 0.0009765625f;
  if (S1 - S2 < THR16 + q) {
    int p = atomicAdd(cnt, 1);
    list[p] = n;
    rpack[p] = 0ull;          // init merge slot for rescue
  }
}

// ---------------- k_rescue: 2-D tasks (8-pt group x 1024-code chunk) --------
// 256 thr/block; thread owns 4 consecutive codes of its chunk (1 float4 of
// embT per channel). d[4 codes][8 pts] = 32 accs. Exact merge across chunks
// via atomicMax(u64). Last block converts winners.
__global__ __launch_bounds__(256, 4) void k_rescue(
    const float* __restrict__ z, const float* __restrict__ embT,
    const float* __restrict__ hneg, const int* __restrict__ list,
    const int* __restrict__ cnt, unsigned long long* __restrict__ rpack,
    int* __restrict__ rdone, int* __restrict__ idxf,
    float* __restrict__ out_idx) {
  __shared__ float zsT[64][8];
  __shared__ int pn[8];
  __shared__ unsigned long long red[4][8];
  __shared__ int lastS;
  const int tid = threadIdx.x;
  const int lane = tid & 63, wv = tid >> 6;
  const int count = *cnt;
  const int ntasks = ((count + 7) >> 3) << 3;   // 8 chunk-tasks per group

  for (int task = blockIdx.x; task < ntasks; task += gridDim.x) {
    const int grp = task >> 3, chunk = task & 7;
    const int base = grp * 8;
    const int P = min(8, count - base);
    __syncthreads();
    if (tid < 8) pn[tid] = list[base + min(tid, P - 1)];
    __syncthreads();
#pragma unroll
    for (int i = tid; i < 512; i += 256) {
      int p = i >> 6, c = i & 63;
      int n = pn[p];
      zsT[c][p] = z[(n >> 10) * 65536 + c * 1024 + (n & 1023)];
    }
    __syncthreads();

    float d[32];
#pragma unroll
    for (int i = 0; i < 32; ++i) d[i] = 0.f;

    const float4* ep = (const float4*)embT + chunk * 256 + tid;
    float4 cur = ep[0];
    for (int c = 0; c < 64; ++c) {
      float4 nxt;
      if (c < 63) nxt = ep[(c + 1) * 2048];
      float4 zpA = *(const float4*)&zsT[c][0];
      float4 zpB = *(const float4*)&zsT[c][4];
#pragma unroll
      for (int k = 0; k < 4; ++k) {
        float e = (k == 0) ? cur.x : (k == 1) ? cur.y : (k == 2) ? cur.z : cur.w;
        float* dp = d + k * 8;
        dp[0] = fmaf(e, zpA.x, dp[0]); dp[1] = fmaf(e, zpA.y, dp[1]);
        dp[2] = fmaf(e, zpA.z, dp[2]); dp[3] = fmaf(e, zpA.w, dp[3]);
        dp[4] = fmaf(e, zpB.x, dp[4]); dp[5] = fmaf(e, zpB.y, dp[5]);
        dp[6] = fmaf(e, zpB.z, dp[6]); dp[7] = fmaf(e, zpB.w, dp[7]);
      }
      if (c < 63) cur = nxt;
    }

    // exact scores -> sortable u64 (score<<32 | 8191-code), max = argmax
    float4 hv = *(const float4*)(hneg + chunk * 1024 + tid * 4);
    unsigned long long best[8];
#pragma unroll
    for (int p = 0; p < 8; ++p) best[p] = 0ull;
#pragma unroll
    for (int k = 0; k < 4; ++k) {
      float hk = (k == 0) ? hv.x : (k == 1) ? hv.y : (k == 2) ? hv.z : hv.w;
      unsigned tag = (unsigned)(8191 - (chunk * 1024 + tid * 4 + k));
#pragma unroll
      for (int p = 0; p < 8; ++p) {
        float sc = d[k * 8 + p] + hk;
        unsigned u = __float_as_uint(sc);
        unsigned sb = (u & 0x80000000u) ? ~u : (u | 0x80000000u);
        unsigned long long pk = ((unsigned long long)sb << 32) | tag;
        best[p] = (pk > best[p]) ? pk : best[p];
      }
    }
#pragma unroll
    for (int off = 32; off >= 1; off >>= 1) {
#pragma unroll
      for (int p = 0; p < 8; ++p) {
        unsigned long long o = __shfl_xor(best[p], off);
        best[p] = (o > best[p]) ? o : best[p];
      }
    }
    if (lane == 0)
#pragma unroll
      for (int p = 0; p < 8; ++p) red[wv][p] = best[p];
    __syncthreads();
    if (tid < 8) {
      unsigned long long b = red[0][tid];
#pragma unroll
      for (int w = 1; w < 4; ++w) b = (red[w][tid] > b) ? red[w][tid] : b;
      if (tid < P) atomicMax(&rpack[base + tid], b);
    }
  }

  // completion: every block signs off; last converts winners
  __syncthreads();
  if (tid == 0) {
    __threadfence();
    lastS = (atomicAdd(rdone, 1) == (int)gridDim.x - 1) ? 1 : 0;
  }
  __syncthreads();
  if (lastS) {
    for (int i = tid; i < count; i += 256) {
      unsigned long long pk = __hip_atomic_load(&rpack[i], __ATOMIC_RELAXED,
                                                __HIP_MEMORY_SCOPE_AGENT);
      int code = 8191 - (int)(pk & 0xFFFFFFFFull);
      int n = list[i];
      idxf[n] = code;
      out_idx[n] = (float)code;
    }
  }
}

// ---------------- k3: gather, ST out, loss partial + fused finalize ----------
__global__ __launch_bounds__(256) void k3_quant(
    const float* __restrict__ z, const float* __restrict__ emb,
    const int* __restrict__ idxf,
    float* __restrict__ out, float* __restrict__ psum, int* __restrict__ done3,
    float* __restrict__ out_loss) {
  int t = blockIdx.x * 256 + threadIdx.x;   // grid 1024 -> 262144 float4 slots
  int g = t * 4;
  int b = g >> 16;
  int c = (g >> 10) & 63;
  int hw = g & 1023;
  int n = (b << 10) | hw;
  float4 zv = *(const float4*)(z + g);
  int4 iv = *(const int4*)(idxf + n);
  float q0 = emb[iv.x * 64 + c];
  float q1 = emb[iv.y * 64 + c];
  float q2 = emb[iv.z * 64 + c];
  float q3 = emb[iv.w * 64 + c];
  float d0 = q0 - zv.x, d1 = q1 - zv.y, d2 = q2 - zv.z, d3 = q3 - zv.w;
  float4 o;
  o.x = zv.x + d0; o.y = zv.y + d1; o.z = zv.z + d2; o.w = zv.w + d3;
  *(float4*)(out + g) = o;
  float val = d0 * d0 + d1 * d1 + d2 * d2 + d3 * d3;
#pragma unroll
  for (int off = 32; off >= 1; off >>= 1) val += __shfl_down(val, off);
  __shared__ float wsum[4];
  __shared__ int lastS;
  int lane = threadIdx.x & 63, wv = threadIdx.x >> 6;
  if (lane == 0) wsum[wv] = val;
  __syncthreads();
  if (threadIdx.x == 0) {
    psum[blockIdx.x] = wsum[0] + wsum[1] + wsum[2] + wsum[3];
    __threadfence();
    lastS = (atomicAdd(done3, 1) == 1023) ? 1 : 0;
  }
  __syncthreads();
  if (lastS) {
    float v = 0.f;
#pragma unroll
    for (int i = 0; i < 4; ++i)
      v += __hip_atomic_load(&psum[threadIdx.x + i * 256], __ATOMIC_RELAXED,
                             __HIP_MEMORY_SCOPE_AGENT);
#pragma unroll
    for (int off = 32; off >= 1; off >>= 1) v += __shfl_down(v, off);
    __syncthreads();
    if (lane == 0) wsum[wv] = v;
    __syncthreads();
    if (threadIdx.x == 0)
      out_loss[0] = 1.25f * (wsum[0] + wsum[1] + wsum[2] + wsum[3]) * (1.0f / 1048576.0f);
  }
}

extern "C" void kernel_launch(void* const* d_in, const int* in_sizes, int n_in,
                              void* d_out, int out_size, void* d_ws, size_t ws_size,
                              hipStream_t stream) {
  const float* z   = (const float*)d_in[0];
  const float* emb = (const float*)d_in[1];
  float* out = (float*)d_out;
  float* ws  = (float*)d_ws;

  float* hneg = ws;                                   // 8192
  unsigned short* e16 = (unsigned short*)(ws + 8192); // 524288 halfs = 262144 f
  float* embT = ws + 8192 + 262144;                   // 524288
  float2* psp = (float2*)(embT + 524288);             // 16*16384 float2
  int* idxf  = (int*)(psp + SPLITS * N_PTS);          // 16384
  int* list  = idxf + N_PTS;                          // 16384
  int* cnt   = list + N_PTS;                          // cnt, rdone, done3 (+pad)
  float* psum = (float*)(cnt + 4);                    // 1024
  unsigned long long* rpack = (unsigned long long*)(psum + 1024);  // 16384 u64

  float* out_idx  = out + 1048576;
  float* out_loss = out + 1048576 + 16384;

  k_pre<<<128, 256, 0, stream>>>(emb, hneg, e16, embT, cnt);
  k1_score<<<dim3(64, SPLITS), 256, 0, stream>>>(z, e16, hneg, psp);
  k2_merge<<<64, 256, 0, stream>>>(psp, idxf, out_idx, list, cnt, rpack);
  k_rescue<<<1024, 256, 0, stream>>>(z, embT, hneg, list, cnt, rpack,
                                     cnt + 1, idxf, out_idx);
  k3_quant<<<1024, 256, 0, stream>>>(z, emb, idxf, out, psum, cnt + 2, out_loss);
}

// Round 15
// 142.317 us; speedup vs baseline: 1.3661x; 1.2453x over previous
//
#include <hip/hip_runtime.h>

// VQ-VAE vector quantizer. Round 15.
// z: [16,64,32,32] f32, emb: [8192,64] f32. N=16384 pts, C=64, V=8192.
// out = [ z_q_st (1048576) | idx as f32 (16384) | vq_loss (1) ]
//
// R14 post-mortem: rescue 2-D fix worked, but the two 1024-block single-line
// sign-offs (rdone, done3) added ~30-40us of serialized atomic tail (G12
// violated, R2 lesson repeated).
// R15: (a) k3/k4 split again (no done3); (b) rescue conversion via PER-GROUP
// done counters (8 tasks/group, 1 cacheline/group) - 8th task converts;
// (c) k1 explicit next-tile B-prefetch (VGPR 64->~80, cap 128).

typedef _Float16 half8 __attribute__((ext_vector_type(8)));
typedef float f32x4 __attribute__((ext_vector_type(4)));

#define N_PTS 16384
#define SPLITS 16
#define THR16 0.08f   // fp16-score error bound (10 sigma), validated R3-R14

// ---------------- k_pre: 4 threads per code row ----------------
__global__ __launch_bounds__(256) void k_pre(const float* __restrict__ emb,
                                             float* __restrict__ hneg,
                                             unsigned short* __restrict__ e16,
                                             float* __restrict__ embT,
                                             int* __restrict__ cnt) {
  int t = blockIdx.x * 256 + threadIdx.x;   // grid 128 -> 32768
  int v = t >> 2, part = t & 3;
  const float4* e4 = (const float4*)(emb + v * 64 + part * 16);
  float row[16];
  float s = 0.f;
#pragma unroll
  for (int i = 0; i < 4; ++i) {
    float4 a = e4[i];
    row[i * 4 + 0] = a.x; row[i * 4 + 1] = a.y;
    row[i * 4 + 2] = a.z; row[i * 4 + 3] = a.w;
    s += a.x * a.x + a.y * a.y + a.z * a.z + a.w * a.w;
  }
  s += __shfl_xor(s, 1);
  s += __shfl_xor(s, 2);
  unsigned short* base = e16 + (v >> 4) * 1024 + (v & 15) * 8;
#pragma unroll
  for (int g = 0; g < 2; ++g) {
    int c8 = part * 2 + g;
    half8 o;
#pragma unroll
    for (int j = 0; j < 8; ++j) o[j] = (_Float16)row[g * 8 + j];
    *(half8*)(base + (c8 >> 2) * 512 + (c8 & 3) * 128) = o;
  }
#pragma unroll
  for (int i = 0; i < 16; ++i) embT[(part * 16 + i) * 8192 + v] = row[i];
  if (part == 0) hneg[v] = -0.5f * s;
  if (t == 0) cnt[0] = 0;
}

// ---------------- k1: MFMA scores, packed-index top-2, B-prefetch ----------
// grid (64, 16). block 256 = 4 waves; wave owns 64 points (4 tiles of 16),
// sweeps 512 codes (32 tiles). 1024 blocks = 4 blocks/CU.
__global__ __launch_bounds__(256, 4) void k1_score(
    const float* __restrict__ z, const unsigned short* __restrict__ e16,
    const float* __restrict__ hneg,
    float2* __restrict__ psp) {
  __shared__ float hs[512];
  const int tid = threadIdx.x;
  const int lane = tid & 63;
  const int wid = tid >> 6;
  const int cl = lane & 15;
  const int gq = lane >> 4;
  const int n0 = blockIdx.x * 256 + wid * 64;
  const int split = blockIdx.y;
  const int vbase = split * 512;

  *(float2*)&hs[tid * 2] = *(const float2*)(hneg + vbase + tid * 2);
  __syncthreads();

  const int b = n0 >> 10;
  const int hw0 = n0 & 1023;

  half8 A[4][2];
  {
    const float* zb = z + b * 65536 + hw0 + cl;
#pragma unroll
    for (int pt = 0; pt < 4; ++pt)
#pragma unroll
      for (int H = 0; H < 2; ++H) {
        half8 a;
#pragma unroll
        for (int j = 0; j < 8; ++j)
          a[j] = (_Float16)zb[pt * 16 + (H * 32 + gq * 8 + j) * 1024];
        A[pt][H] = a;
      }
  }

  float s1[4][4], s2[4][4];
#pragma unroll
  for (int pt = 0; pt < 4; ++pt)
#pragma unroll
    for (int r = 0; r < 4; ++r) { s1[pt][r] = -3.0e38f; s2[pt][r] = -3.0e38f; }

  const unsigned short* bp = e16 + vbase * 64 + lane * 8;
  int idxb = 8191 - (vbase + cl);

  // software pipeline: B for tile T+1 in flight during tile T's MFMA+epilogue
  half8 B0 = *(const half8*)bp;
  half8 B1 = *(const half8*)(bp + 512);

  for (int T = 0; T < 32; ++T) {
    half8 nB0, nB1;
    if (T < 31) {
      nB0 = *(const half8*)(bp + 1024);
      nB1 = *(const half8*)(bp + 1536);
    }
    const float nh = hs[T * 16 + cl];
    f32x4 C0;
    C0[0] = nh; C0[1] = nh; C0[2] = nh; C0[3] = nh;

#pragma unroll
    for (int pt = 0; pt < 4; ++pt) {
      f32x4 acc = __builtin_amdgcn_mfma_f32_16x16x32_f16(A[pt][0], B0, C0, 0, 0, 0);
      acc = __builtin_amdgcn_mfma_f32_16x16x32_f16(A[pt][1], B1, acc, 0, 0, 0);
#pragma unroll
      for (int r = 0; r < 4; ++r) {
        unsigned u = (__float_as_uint(acc[r]) & 0xFFFFE000u) | (unsigned)idxb;
        float p = __uint_as_float(u);
        s2[pt][r] = __builtin_amdgcn_fmed3f(p, s1[pt][r], s2[pt][r]);
        s1[pt][r] = fmaxf(s1[pt][r], p);
      }
    }
    idxb -= 16;
    B0 = nB0; B1 = nB1;
    bp += 1024;
  }

#pragma unroll
  for (int off = 8; off >= 1; off >>= 1) {
#pragma unroll
    for (int pt = 0; pt < 4; ++pt)
#pragma unroll
      for (int r = 0; r < 4; ++r) {
        float os = __shfl_xor(s1[pt][r], off);
        float o2 = __shfl_xor(s2[pt][r], off);
        s2[pt][r] = fmaxf(fmaxf(s2[pt][r], o2), fminf(s1[pt][r], os));
        s1[pt][r] = fmaxf(s1[pt][r], os);
      }
  }

  if (cl == 0) {
#pragma unroll
    for (int pt = 0; pt < 4; ++pt)
#pragma unroll
      for (int r = 0; r < 4; ++r) {
        int n = n0 + pt * 16 + gq * 4 + r;
        float2 o; o.x = s1[pt][r]; o.y = s2[pt][r];
        psp[split * N_PTS + n] = o;
      }
  }
}

// ---------------- k2: merge splits (packed), exact-q margin, emit idx --------
__global__ __launch_bounds__(256) void k2_merge(
    const float2* __restrict__ psp,
    int* __restrict__ idxf, float* __restrict__ out_idx,
    int* __restrict__ list, int* __restrict__ cnt,
    unsigned long long* __restrict__ rpack, int* __restrict__ gdone) {
  int n = blockIdx.x * 256 + threadIdx.x;   // grid 64 -> 16384
  float S1 = -3.0e38f, S2 = -3.0e38f;
#pragma unroll
  for (int s = 0; s < SPLITS; ++s) {
    float2 a = psp[s * N_PTS + n];
    if (a.x > S1) { S2 = fmaxf(fmaxf(S2, a.y), S1); S1 = a.x; }
    else          { S2 = fmaxf(S2, a.x); }
  }
  int I1 = 8191 - (int)(__float_as_uint(S1) & 0x1FFFu);
  idxf[n] = I1;
  out_idx[n] = (float)I1;
  // packing truncation error <= |S|*2^-10 per score; compensate exactly
  float q = fmaxf(fabsf(S1), fabsf(S2)) * 0.0009765625f;
  if (S1 - S2 < THR16 + q) {
    int p = atomicAdd(cnt, 1);
    list[p] = n;
    rpack[p] = 0ull;
    gdone[(p >> 3) * 16] = 0;   // group counter, 1 cacheline per group
  }
}

// ---------------- k_rescue: 2-D tasks, per-group completion ----------------
// task = (8-pt group) x (1024-code chunk); 8 tasks/group. Exact merge via
// atomicMax(u64); 8th finishing task of a group converts its 8 winners.
__global__ __launch_bounds__(256, 4) void k_rescue(
    const float* __restrict__ z, const float* __restrict__ embT,
    const float* __restrict__ hneg, const int* __restrict__ list,
    const int* __restrict__ cnt, unsigned long long* __restrict__ rpack,
    int* __restrict__ gdone, int* __restrict__ idxf,
    float* __restrict__ out_idx) {
  __shared__ float zsT[64][8];
  __shared__ int pn[8];
  __shared__ unsigned long long red[4][8];
  __shared__ int lastS;
  const int tid = threadIdx.x;
  const int lane = tid & 63, wv = tid >> 6;
  const int count = *cnt;
  const int ntasks = ((count + 7) >> 3) << 3;

  for (int task = blockIdx.x; task < ntasks; task += gridDim.x) {
    const int grp = task >> 3, chunk = task & 7;
    const int base = grp * 8;
    const int P = min(8, count - base);
    __syncthreads();
    if (tid < 8) pn[tid] = list[base + min(tid, P - 1)];
    __syncthreads();
#pragma unroll
    for (int i = tid; i < 512; i += 256) {
      int p = i >> 6, c = i & 63;
      int n = pn[p];
      zsT[c][p] = z[(n >> 10) * 65536 + c * 1024 + (n & 1023)];
    }
    __syncthreads();

    float d[32];
#pragma unroll
    for (int i = 0; i < 32; ++i) d[i] = 0.f;

    const float4* ep = (const float4*)embT + chunk * 256 + tid;
    float4 cur = ep[0];
    for (int c = 0; c < 64; ++c) {
      float4 nxt;
      if (c < 63) nxt = ep[(c + 1) * 2048];
      float4 zpA = *(const float4*)&zsT[c][0];
      float4 zpB = *(const float4*)&zsT[c][4];
#pragma unroll
      for (int k = 0; k < 4; ++k) {
        float e = (k == 0) ? cur.x : (k == 1) ? cur.y : (k == 2) ? cur.z : cur.w;
        float* dp = d + k * 8;
        dp[0] = fmaf(e, zpA.x, dp[0]); dp[1] = fmaf(e, zpA.y, dp[1]);
        dp[2] = fmaf(e, zpA.z, dp[2]); dp[3] = fmaf(e, zpA.w, dp[3]);
        dp[4] = fmaf(e, zpB.x, dp[4]); dp[5] = fmaf(e, zpB.y, dp[5]);
        dp[6] = fmaf(e, zpB.z, dp[6]); dp[7] = fmaf(e, zpB.w, dp[7]);
      }
      if (c < 63) cur = nxt;
    }

    // exact scores -> sortable u64 (score<<32 | 8191-code), max = argmax
    float4 hv = *(const float4*)(hneg + chunk * 1024 + tid * 4);
    unsigned long long best[8];
#pragma unroll
    for (int p = 0; p < 8; ++p) best[p] = 0ull;
#pragma unroll
    for (int k = 0; k < 4; ++k) {
      float hk = (k == 0) ? hv.x : (k == 1) ? hv.y : (k == 2) ? hv.z : hv.w;
      unsigned tag = (unsigned)(8191 - (chunk * 1024 + tid * 4 + k));
#pragma unroll
      for (int p = 0; p < 8; ++p) {
        float sc = d[k * 8 + p] + hk;
        unsigned u = __float_as_uint(sc);
        unsigned sb = (u & 0x80000000u) ? ~u : (u | 0x80000000u);
        unsigned long long pk = ((unsigned long long)sb << 32) | tag;
        best[p] = (pk > best[p]) ? pk : best[p];
      }
    }
#pragma unroll
    for (int off = 32; off >= 1; off >>= 1) {
#pragma unroll
      for (int p = 0; p < 8; ++p) {
        unsigned long long o = __shfl_xor(best[p], off);
        best[p] = (o > best[p]) ? o : best[p];
      }
    }
    if (lane == 0)
#pragma unroll
      for (int p = 0; p < 8; ++p) red[wv][p] = best[p];
    __syncthreads();
    if (tid < 8) {
      unsigned long long bmax = red[0][tid];
#pragma unroll
      for (int w = 1; w < 4; ++w) bmax = (red[w][tid] > bmax) ? red[w][tid] : bmax;
      if (tid < P) atomicMax(&rpack[base + tid], bmax);
    }
    __syncthreads();
    // per-group completion: 8th task converts (release-acquire on gdone)
    if (tid == 0) {
      lastS = (__hip_atomic_fetch_add(&gdone[grp * 16], 1, __ATOMIC_ACQ_REL,
                                      __HIP_MEMORY_SCOPE_AGENT) == 7) ? 1 : 0;
    }
    __syncthreads();
    if (lastS && tid < P) {
      unsigned long long pk = __hip_atomic_load(&rpack[base + tid],
                                                __ATOMIC_RELAXED,
                                                __HIP_MEMORY_SCOPE_AGENT);
      int code = 8191 - (int)(pk & 0xFFFFFFFFull);
      int n = pn[tid];
      idxf[n] = code;
      out_idx[n] = (float)code;
    }
  }
}

// ---------------- k3: gather, straight-through out, block partial loss --------
__global__ __launch_bounds__(256) void k3_quant(
    const float* __restrict__ z, const float* __restrict__ emb,
    const int* __restrict__ idxf,
    float* __restrict__ out, float* __restrict__ psum) {
  int t = blockIdx.x * 256 + threadIdx.x;   // grid 1024 -> 262144 float4 slots
  int g = t * 4;
  int b = g >> 16;
  int c = (g >> 10) & 63;
  int hw = g & 1023;
  int n = (b << 10) | hw;
  float4 zv = *(const float4*)(z + g);
  int4 iv = *(const int4*)(idxf + n);
  float q0 = emb[iv.x * 64 + c];
  float q1 = emb[iv.y * 64 + c];
  float q2 = emb[iv.z * 64 + c];
  float q3 = emb[iv.w * 64 + c];
  float d0 = q0 - zv.x, d1 = q1 - zv.y, d2 = q2 - zv.z, d3 = q3 - zv.w;
  float4 o;
  o.x = zv.x + d0; o.y = zv.y + d1; o.z = zv.z + d2; o.w = zv.w + d3;
  *(float4*)(out + g) = o;
  float val = d0 * d0 + d1 * d1 + d2 * d2 + d3 * d3;
#pragma unroll
  for (int off = 32; off >= 1; off >>= 1) val += __shfl_down(val, off);
  __shared__ float wsum[4];
  int lane = threadIdx.x & 63, wv = threadIdx.x >> 6;
  if (lane == 0) wsum[wv] = val;
  __syncthreads();
  if (threadIdx.x == 0)
    psum[blockIdx.x] = wsum[0] + wsum[1] + wsum[2] + wsum[3];
}

// ---------------- k4: final loss reduce (1024 partials) ----------------
__global__ __launch_bounds__(256) void k4_loss(const float* __restrict__ psum,
                                               float* __restrict__ out_loss) {
  int tid = threadIdx.x;
  float val = psum[tid] + psum[tid + 256] + psum[tid + 512] + psum[tid + 768];
#pragma unroll
  for (int off = 32; off >= 1; off >>= 1) val += __shfl_down(val, off);
  __shared__ float wsum[4];
  int lane = tid & 63, wv = tid >> 6;
  if (lane == 0) wsum[wv] = val;
  __syncthreads();
  if (tid == 0)
    out_loss[0] = 1.25f * (wsum[0] + wsum[1] + wsum[2] + wsum[3]) * (1.0f / 1048576.0f);
}

extern "C" void kernel_launch(void* const* d_in, const int* in_sizes, int n_in,
                              void* d_out, int out_size, void* d_ws, size_t ws_size,
                              hipStream_t stream) {
  const float* z   = (const float*)d_in[0];
  const float* emb = (const float*)d_in[1];
  float* out = (float*)d_out;
  float* ws  = (float*)d_ws;

  float* hneg = ws;                                   // 8192
  unsigned short* e16 = (unsigned short*)(ws + 8192); // 524288 halfs = 262144 f
  float* embT = ws + 8192 + 262144;                   // 524288
  float2* psp = (float2*)(embT + 524288);             // 16*16384 float2
  int* idxf  = (int*)(psp + SPLITS * N_PTS);          // 16384
  int* list  = idxf + N_PTS;                          // 16384
  int* cnt   = list + N_PTS;                          // 1 (+pad to 4)
  float* psum = (float*)(cnt + 4);                    // 1024
  unsigned long long* rpack = (unsigned long long*)(psum + 1024);  // 16384 u64
  int* gdone = (int*)(rpack + N_PTS);                 // 2048*16 ints (padded)

  float* out_idx  = out + 1048576;
  float* out_loss = out + 1048576 + 16384;

  k_pre<<<128, 256, 0, stream>>>(emb, hneg, e16, embT, cnt);
  k1_score<<<dim3(64, SPLITS), 256, 0, stream>>>(z, e16, hneg, psp);
  k2_merge<<<64, 256, 0, stream>>>(psp, idxf, out_idx, list, cnt, rpack, gdone);
  k_rescue<<<1024, 256, 0, stream>>>(z, embT, hneg, list, cnt, rpack,
                                     gdone, idxf, out_idx);
  k3_quant<<<1024, 256, 0, stream>>>(z, emb, idxf, out, psum);
  k4_loss<<<1, 256, 0, stream>>>(psum, out_loss);
}

// Round 16
// 141.509 us; speedup vs baseline: 1.3739x; 1.0057x over previous
//
#include <hip/hip_runtime.h>

// VQ-VAE vector quantizer. Round 16.
// z: [16,64,32,32] f32, emb: [8192,64] f32. N=16384 pts, C=64, V=8192.
// out = [ z_q_st (1048576) | idx as f32 (16384) | vq_loss (1) ]
//
// R15 post-mortem: total 142.3 (best). k1 stuck at 43.5 with VGPR_Count=52 —
// live state is >=80 regs, so compiler parked A/s1/s2 in AGPRs; every
// epilogue op pays v_accvgpr_read/write (~2-4 hidden VALU/score = the 3x gap
// between 3-op arithmetic and measured VALU issue).
// R16 (single variable): k1 launch_bounds (256,4)->(256,3): VGPR cap 128->170
// so state stays in arch VGPRs. Occupancy 4->3 blocks/CU (k1 is TLP-
// insensitive per R7/R10). Everything else identical to R15.

typedef _Float16 half8 __attribute__((ext_vector_type(8)));
typedef float f32x4 __attribute__((ext_vector_type(4)));

#define N_PTS 16384
#define SPLITS 16
#define THR16 0.08f   // fp16-score error bound (10 sigma), validated R3-R15

// ---------------- k_pre: 4 threads per code row ----------------
__global__ __launch_bounds__(256) void k_pre(const float* __restrict__ emb,
                                             float* __restrict__ hneg,
                                             unsigned short* __restrict__ e16,
                                             float* __restrict__ embT,
                                             int* __restrict__ cnt) {
  int t = blockIdx.x * 256 + threadIdx.x;   // grid 128 -> 32768
  int v = t >> 2, part = t & 3;
  const float4* e4 = (const float4*)(emb + v * 64 + part * 16);
  float row[16];
  float s = 0.f;
#pragma unroll
  for (int i = 0; i < 4; ++i) {
    float4 a = e4[i];
    row[i * 4 + 0] = a.x; row[i * 4 + 1] = a.y;
    row[i * 4 + 2] = a.z; row[i * 4 + 3] = a.w;
    s += a.x * a.x + a.y * a.y + a.z * a.z + a.w * a.w;
  }
  s += __shfl_xor(s, 1);
  s += __shfl_xor(s, 2);
  unsigned short* base = e16 + (v >> 4) * 1024 + (v & 15) * 8;
#pragma unroll
  for (int g = 0; g < 2; ++g) {
    int c8 = part * 2 + g;
    half8 o;
#pragma unroll
    for (int j = 0; j < 8; ++j) o[j] = (_Float16)row[g * 8 + j];
    *(half8*)(base + (c8 >> 2) * 512 + (c8 & 3) * 128) = o;
  }
#pragma unroll
  for (int i = 0; i < 16; ++i) embT[(part * 16 + i) * 8192 + v] = row[i];
  if (part == 0) hneg[v] = -0.5f * s;
  if (t == 0) cnt[0] = 0;
}

// ---------------- k1: MFMA scores, packed-index top-2, B-prefetch ----------
// grid (64, 16). block 256 = 4 waves; wave owns 64 points (4 tiles of 16),
// sweeps 512 codes (32 tiles). launch_bounds (256,3): VGPR cap ~170 so
// A/s1/s2 stay in arch VGPRs (no AGPR round-trips). 3 blocks/CU.
__global__ __launch_bounds__(256, 3) void k1_score(
    const float* __restrict__ z, const unsigned short* __restrict__ e16,
    const float* __restrict__ hneg,
    float2* __restrict__ psp) {
  __shared__ float hs[512];
  const int tid = threadIdx.x;
  const int lane = tid & 63;
  const int wid = tid >> 6;
  const int cl = lane & 15;
  const int gq = lane >> 4;
  const int n0 = blockIdx.x * 256 + wid * 64;
  const int split = blockIdx.y;
  const int vbase = split * 512;

  *(float2*)&hs[tid * 2] = *(const float2*)(hneg + vbase + tid * 2);
  __syncthreads();

  const int b = n0 >> 10;
  const int hw0 = n0 & 1023;

  half8 A[4][2];
  {
    const float* zb = z + b * 65536 + hw0 + cl;
#pragma unroll
    for (int pt = 0; pt < 4; ++pt)
#pragma unroll
      for (int H = 0; H < 2; ++H) {
        half8 a;
#pragma unroll
        for (int j = 0; j < 8; ++j)
          a[j] = (_Float16)zb[pt * 16 + (H * 32 + gq * 8 + j) * 1024];
        A[pt][H] = a;
      }
  }

  float s1[4][4], s2[4][4];
#pragma unroll
  for (int pt = 0; pt < 4; ++pt)
#pragma unroll
    for (int r = 0; r < 4; ++r) { s1[pt][r] = -3.0e38f; s2[pt][r] = -3.0e38f; }

  const unsigned short* bp = e16 + vbase * 64 + lane * 8;
  int idxb = 8191 - (vbase + cl);

  // software pipeline: B for tile T+1 in flight during tile T's MFMA+epilogue
  half8 B0 = *(const half8*)bp;
  half8 B1 = *(const half8*)(bp + 512);

  for (int T = 0; T < 32; ++T) {
    half8 nB0, nB1;
    if (T < 31) {
      nB0 = *(const half8*)(bp + 1024);
      nB1 = *(const half8*)(bp + 1536);
    }
    const float nh = hs[T * 16 + cl];
    f32x4 C0;
    C0[0] = nh; C0[1] = nh; C0[2] = nh; C0[3] = nh;

#pragma unroll
    for (int pt = 0; pt < 4; ++pt) {
      f32x4 acc = __builtin_amdgcn_mfma_f32_16x16x32_f16(A[pt][0], B0, C0, 0, 0, 0);
      acc = __builtin_amdgcn_mfma_f32_16x16x32_f16(A[pt][1], B1, acc, 0, 0, 0);
#pragma unroll
      for (int r = 0; r < 4; ++r) {
        unsigned u = (__float_as_uint(acc[r]) & 0xFFFFE000u) | (unsigned)idxb;
        float p = __uint_as_float(u);
        s2[pt][r] = __builtin_amdgcn_fmed3f(p, s1[pt][r], s2[pt][r]);
        s1[pt][r] = fmaxf(s1[pt][r], p);
      }
    }
    idxb -= 16;
    B0 = nB0; B1 = nB1;
    bp += 1024;
  }

#pragma unroll
  for (int off = 8; off >= 1; off >>= 1) {
#pragma unroll
    for (int pt = 0; pt < 4; ++pt)
#pragma unroll
      for (int r = 0; r < 4; ++r) {
        float os = __shfl_xor(s1[pt][r], off);
        float o2 = __shfl_xor(s2[pt][r], off);
        s2[pt][r] = fmaxf(fmaxf(s2[pt][r], o2), fminf(s1[pt][r], os));
        s1[pt][r] = fmaxf(s1[pt][r], os);
      }
  }

  if (cl == 0) {
#pragma unroll
    for (int pt = 0; pt < 4; ++pt)
#pragma unroll
      for (int r = 0; r < 4; ++r) {
        int n = n0 + pt * 16 + gq * 4 + r;
        float2 o; o.x = s1[pt][r]; o.y = s2[pt][r];
        psp[split * N_PTS + n] = o;
      }
  }
}

// ---------------- k2: merge splits (packed), exact-q margin, emit idx --------
__global__ __launch_bounds__(256) void k2_merge(
    const float2* __restrict__ psp,
    int* __restrict__ idxf, float* __restrict__ out_idx,
    int* __restrict__ list, int* __restrict__ cnt,
    unsigned long long* __restrict__ rpack, int* __restrict__ gdone) {
  int n = blockIdx.x * 256 + threadIdx.x;   // grid 64 -> 16384
  float S1 = -3.0e38f, S2 = -3.0e38f;
#pragma unroll
  for (int s = 0; s < SPLITS; ++s) {
    float2 a = psp[s * N_PTS + n];
    if (a.x > S1) { S2 = fmaxf(fmaxf(S2, a.y), S1); S1 = a.x; }
    else          { S2 = fmaxf(S2, a.x); }
  }
  int I1 = 8191 - (int)(__float_as_uint(S1) & 0x1FFFu);
  idxf[n] = I1;
  out_idx[n] = (float)I1;
  // packing truncation error <= |S|*2^-10 per score; compensate exactly
  float q = fmaxf(fabsf(S1), fabsf(S2)) * 0.0009765625f;
  if (S1 - S2 < THR16 + q) {
    int p = atomicAdd(cnt, 1);
    list[p] = n;
    rpack[p] = 0ull;
    gdone[(p >> 3) * 16] = 0;   // group counter, 1 cacheline per group
  }
}

// ---------------- k_rescue: 2-D tasks, per-group completion ----------------
// task = (8-pt group) x (1024-code chunk); 8 tasks/group. Exact merge via
// atomicMax(u64); 8th finishing task of a group converts its 8 winners.
__global__ __launch_bounds__(256, 4) void k_rescue(
    const float* __restrict__ z, const float* __restrict__ embT,
    const float* __restrict__ hneg, const int* __restrict__ list,
    const int* __restrict__ cnt, unsigned long long* __restrict__ rpack,
    int* __restrict__ gdone, int* __restrict__ idxf,
    float* __restrict__ out_idx) {
  __shared__ float zsT[64][8];
  __shared__ int pn[8];
  __shared__ unsigned long long red[4][8];
  __shared__ int lastS;
  const int tid = threadIdx.x;
  const int lane = tid & 63, wv = tid >> 6;
  const int count = *cnt;
  const int ntasks = ((count + 7) >> 3) << 3;

  for (int task = blockIdx.x; task < ntasks; task += gridDim.x) {
    const int grp = task >> 3, chunk = task & 7;
    const int base = grp * 8;
    const int P = min(8, count - base);
    __syncthreads();
    if (tid < 8) pn[tid] = list[base + min(tid, P - 1)];
    __syncthreads();
#pragma unroll
    for (int i = tid; i < 512; i += 256) {
      int p = i >> 6, c = i & 63;
      int n = pn[p];
      zsT[c][p] = z[(n >> 10) * 65536 + c * 1024 + (n & 1023)];
    }
    __syncthreads();

    float d[32];
#pragma unroll
    for (int i = 0; i < 32; ++i) d[i] = 0.f;

    const float4* ep = (const float4*)embT + chunk * 256 + tid;
    float4 cur = ep[0];
    for (int c = 0; c < 64; ++c) {
      float4 nxt;
      if (c < 63) nxt = ep[(c + 1) * 2048];
      float4 zpA = *(const float4*)&zsT[c][0];
      float4 zpB = *(const float4*)&zsT[c][4];
#pragma unroll
      for (int k = 0; k < 4; ++k) {
        float e = (k == 0) ? cur.x : (k == 1) ? cur.y : (k == 2) ? cur.z : cur.w;
        float* dp = d + k * 8;
        dp[0] = fmaf(e, zpA.x, dp[0]); dp[1] = fmaf(e, zpA.y, dp[1]);
        dp[2] = fmaf(e, zpA.z, dp[2]); dp[3] = fmaf(e, zpA.w, dp[3]);
        dp[4] = fmaf(e, zpB.x, dp[4]); dp[5] = fmaf(e, zpB.y, dp[5]);
        dp[6] = fmaf(e, zpB.z, dp[6]); dp[7] = fmaf(e, zpB.w, dp[7]);
      }
      if (c < 63) cur = nxt;
    }

    // exact scores -> sortable u64 (score<<32 | 8191-code), max = argmax
    float4 hv = *(const float4*)(hneg + chunk * 1024 + tid * 4);
    unsigned long long best[8];
#pragma unroll
    for (int p = 0; p < 8; ++p) best[p] = 0ull;
#pragma unroll
    for (int k = 0; k < 4; ++k) {
      float hk = (k == 0) ? hv.x : (k == 1) ? hv.y : (k == 2) ? hv.z : hv.w;
      unsigned tag = (unsigned)(8191 - (chunk * 1024 + tid * 4 + k));
#pragma unroll
      for (int p = 0; p < 8; ++p) {
        float sc = d[k * 8 + p] + hk;
        unsigned u = __float_as_uint(sc);
        unsigned sb = (u & 0x80000000u) ? ~u : (u | 0x80000000u);
        unsigned long long pk = ((unsigned long long)sb << 32) | tag;
        best[p] = (pk > best[p]) ? pk : best[p];
      }
    }
#pragma unroll
    for (int off = 32; off >= 1; off >>= 1) {
#pragma unroll
      for (int p = 0; p < 8; ++p) {
        unsigned long long o = __shfl_xor(best[p], off);
        best[p] = (o > best[p]) ? o : best[p];
      }
    }
    if (lane == 0)
#pragma unroll
      for (int p = 0; p < 8; ++p) red[wv][p] = best[p];
    __syncthreads();
    if (tid < 8) {
      unsigned long long bmax = red[0][tid];
#pragma unroll
      for (int w = 1; w < 4; ++w) bmax = (red[w][tid] > bmax) ? red[w][tid] : bmax;
      if (tid < P) atomicMax(&rpack[base + tid], bmax);
    }
    __syncthreads();
    // per-group completion: 8th task converts (release-acquire on gdone)
    if (tid == 0) {
      lastS = (__hip_atomic_fetch_add(&gdone[grp * 16], 1, __ATOMIC_ACQ_REL,
                                      __HIP_MEMORY_SCOPE_AGENT) == 7) ? 1 : 0;
    }
    __syncthreads();
    if (lastS && tid < P) {
      unsigned long long pk = __hip_atomic_load(&rpack[base + tid],
                                                __ATOMIC_RELAXED,
                                                __HIP_MEMORY_SCOPE_AGENT);
      int code = 8191 - (int)(pk & 0xFFFFFFFFull);
      int n = pn[tid];
      idxf[n] = code;
      out_idx[n] = (float)code;
    }
  }
}

// ---------------- k3: gather, straight-through out, block partial loss --------
__global__ __launch_bounds__(256) void k3_quant(
    const float* __restrict__ z, const float* __restrict__ emb,
    const int* __restrict__ idxf,
    float* __restrict__ out, float* __restrict__ psum) {
  int t = blockIdx.x * 256 + threadIdx.x;   // grid 1024 -> 262144 float4 slots
  int g = t * 4;
  int b = g >> 16;
  int c = (g >> 10) & 63;
  int hw = g & 1023;
  int n = (b << 10) | hw;
  float4 zv = *(const float4*)(z + g);
  int4 iv = *(const int4*)(idxf + n);
  float q0 = emb[iv.x * 64 + c];
  float q1 = emb[iv.y * 64 + c];
  float q2 = emb[iv.z * 64 + c];
  float q3 = emb[iv.w * 64 + c];
  float d0 = q0 - zv.x, d1 = q1 - zv.y, d2 = q2 - zv.z, d3 = q3 - zv.w;
  float4 o;
  o.x = zv.x + d0; o.y = zv.y + d1; o.z = zv.z + d2; o.w = zv.w + d3;
  *(float4*)(out + g) = o;
  float val = d0 * d0 + d1 * d1 + d2 * d2 + d3 * d3;
#pragma unroll
  for (int off = 32; off >= 1; off >>= 1) val += __shfl_down(val, off);
  __shared__ float wsum[4];
  int lane = threadIdx.x & 63, wv = threadIdx.x >> 6;
  if (lane == 0) wsum[wv] = val;
  __syncthreads();
  if (threadIdx.x == 0)
    psum[blockIdx.x] = wsum[0] + wsum[1] + wsum[2] + wsum[3];
}

// ---------------- k4: final loss reduce (1024 partials) ----------------
__global__ __launch_bounds__(256) void k4_loss(const float* __restrict__ psum,
                                               float* __restrict__ out_loss) {
  int tid = threadIdx.x;
  float val = psum[tid] + psum[tid + 256] + psum[tid + 512] + psum[tid + 768];
#pragma unroll
  for (int off = 32; off >= 1; off >>= 1) val += __shfl_down(val, off);
  __shared__ float wsum[4];
  int lane = tid & 63, wv = tid >> 6;
  if (lane == 0) wsum[wv] = val;
  __syncthreads();
  if (tid == 0)
    out_loss[0] = 1.25f * (wsum[0] + wsum[1] + wsum[2] + wsum[3]) * (1.0f / 1048576.0f);
}

extern "C" void kernel_launch(void* const* d_in, const int* in_sizes, int n_in,
                              void* d_out, int out_size, void* d_ws, size_t ws_size,
                              hipStream_t stream) {
  const float* z   = (const float*)d_in[0];
  const float* emb = (const float*)d_in[1];
  float* out = (float*)d_out;
  float* ws  = (float*)d_ws;

  float* hneg = ws;                                   // 8192
  unsigned short* e16 = (unsigned short*)(ws + 8192); // 524288 halfs = 262144 f
  float* embT = ws + 8192 + 262144;                   // 524288
  float2* psp = (float2*)(embT + 524288);             // 16*16384 float2
  int* idxf  = (int*)(psp + SPLITS * N_PTS);          // 16384
  int* list  = idxf + N_PTS;                          // 16384
  int* cnt   = list + N_PTS;                          // 1 (+pad to 4)
  float* psum = (float*)(cnt + 4);                    // 1024
  unsigned long long* rpack = (unsigned long long*)(psum + 1024);  // 16384 u64
  int* gdone = (int*)(rpack + N_PTS);                 // 2048*16 ints (padded)

  float* out_idx  = out + 1048576;
  float* out_loss = out + 1048576 + 16384;

  k_pre<<<128, 256, 0, stream>>>(emb, hneg, e16, embT, cnt);
  k1_score<<<dim3(64, SPLITS), 256, 0, stream>>>(z, e16, hneg, psp);
  k2_merge<<<64, 256, 0, stream>>>(psp, idxf, out_idx, list, cnt, rpack, gdone);
  k_rescue<<<1024, 256, 0, stream>>>(z, embT, hneg, list, cnt, rpack,
                                     gdone, idxf, out_idx);
  k3_quant<<<1024, 256, 0, stream>>>(z, emb, idxf, out, psum);
  k4_loss<<<1, 256, 0, stream>>>(psum, out_loss);
}